// Round 4
// baseline (116.904 us; speedup 1.0000x reference)
//
#include <hip/hip_runtime.h>

typedef float f32x2 __attribute__((ext_vector_type(2)));

#define BLOCK 256
#define P 4                 // A-points per thread
#define NWAVE 4             // j-slice split across the block's waves
#define NPTS 4096
#define NPAIR 2048          // j-pair records per (cloud,batch)
#define SLICE_PAIRS 512     // records per wave slice
#define CHUNK 8             // records per unrolled chunk

// ---------------- pre-pass: pack clouds into j-pair records ----------------
// record (32B): {x0,x1, y0,y1, z0,z1, h0,h1}, h = |p|^2 / 2
__global__ __launch_bounds__(256) void pack_kernel(
    const float* __restrict__ points,
    const float* __restrict__ gts,
    float* __restrict__ pk)          // [2][32][NPAIR][8]
{
    const int tid = blockIdx.x * 256 + threadIdx.x;   // 0 .. 2*32*2048-1
    const int c   = tid >> 16;                        // cloud (65536 recs each)
    const int rem = tid & 65535;
    const int b   = rem >> 11;
    const int jp  = rem & 2047;
    const float* src = (c ? gts : points) + ((size_t)b * NPTS + 2 * jp) * 3;
    const float x0 = src[0], y0 = src[1], z0 = src[2];
    const float x1 = src[3], y1 = src[4], z1 = src[5];
    const float h0 = 0.5f * (x0 * x0 + y0 * y0 + z0 * z0);
    const float h1 = 0.5f * (x1 * x1 + y1 * y1 + z1 * z1);
    float4* dst = (float4*)(pk + (size_t)tid * 8);
    dst[0] = make_float4(x0, x1, y0, y1);
    dst[1] = make_float4(z0, z1, h0, h1);
}

// ---------------- main: B from SGPRs, zero LDS in inner loop ----------------
__global__ __launch_bounds__(256) void chamfer_main(
    const float* __restrict__ points,
    const float* __restrict__ gts,
    const float* __restrict__ pk,    // packed records
    float* __restrict__ sums)        // [2]
{
    const int b   = blockIdx.y;
    const int dir = blockIdx.z;
    const float* Ab = (dir ? gts : points) + (size_t)b * NPTS * 3;

    const int w = threadIdx.x >> 6;
    const int l = threadIdx.x & 63;
    const int wu = __builtin_amdgcn_readfirstlane(w);   // wave-uniform

    // B cloud: dir==0 -> gts (cloud 1), dir==1 -> points (cloud 0)
    const float* __restrict__ rec0 =
        pk + (((size_t)(dir ^ 1) * 32 + b) * NPAIR + (size_t)wu * SLICE_PAIRS) * 8;

    const int pbase = blockIdx.x * BLOCK;

    // pre-negated, half-duplicated A operands (loop-invariant)
    f32x2 nax[P], nay[P], naz[P], hap[P];
    float mind[P];
    #pragma unroll
    for (int p = 0; p < P; ++p) {
        const int i = pbase + p * 64 + l;
        const float ax = Ab[i * 3 + 0];
        const float ay = Ab[i * 3 + 1];
        const float az = Ab[i * 3 + 2];
        const float ha = 0.5f * (ax * ax + ay * ay + az * az);
        nax[p] = (f32x2){-ax, -ax};
        nay[p] = (f32x2){-ay, -ay};
        naz[p] = (f32x2){-az, -az};
        hap[p] = (f32x2){ha, ha};
        mind[p] = 3.4e38f;
    }

    for (int r = 0; r < SLICE_PAIRS; r += CHUNK) {
        const float* __restrict__ rec = rec0 + r * 8;   // uniform address
        #pragma unroll
        for (int k = 0; k < CHUNK; ++k) {
            const f32x2 gx = *(const f32x2*)(rec + k * 8 + 0);
            const f32x2 gy = *(const f32x2*)(rec + k * 8 + 2);
            const f32x2 gz = *(const f32x2*)(rec + k * 8 + 4);
            const f32x2 gh = *(const f32x2*)(rec + k * 8 + 6);
            #pragma unroll
            for (int p = 0; p < P; ++p) {
                f32x2 t;
                asm("v_pk_fma_f32 %0, %1, %2, %3"
                    : "=v"(t) : "v"(nax[p]), "s"(gx), "v"(hap[p]));
                asm("v_pk_fma_f32 %0, %1, %2, %0"
                    : "+v"(t) : "v"(nay[p]), "s"(gy));
                asm("v_pk_fma_f32 %0, %1, %2, %0"
                    : "+v"(t) : "v"(naz[p]), "s"(gz));
                f32x2 q;   // q = hb + (ha - a.b) = d^2/2
                asm("v_pk_add_f32 %0, %1, %2"
                    : "=v"(q) : "s"(gh), "v"(t));
                asm("v_min3_f32 %0, %0, %1, %2"
                    : "+v"(mind[p]) : "v"(q.x), "v"(q.y));
            }
        }
    }

    // combine the 4 waves' slice-partial mins
    __shared__ float pmin[NWAVE][BLOCK];
    #pragma unroll
    for (int p = 0; p < P; ++p)
        pmin[w][p * 64 + l] = mind[p];
    __syncthreads();

    const int t = threadIdx.x;
    const float q = fminf(fminf(pmin[0][t], pmin[1][t]),
                          fminf(pmin[2][t], pmin[3][t]));
    float v = sqrtf(fmaxf(q + q, 0.0f));   // d = sqrt(2q)

    for (int off = 32; off > 0; off >>= 1)
        v += __shfl_down(v, off);

    __shared__ float wsum[NWAVE];
    if (l == 0) wsum[w] = v;
    __syncthreads();
    if (t == 0)
        atomicAdd(sums + dir, wsum[0] + wsum[1] + wsum[2] + wsum[3]);
}

__global__ void chamfer_finalize_kernel(const float* __restrict__ sums,
                                        float* __restrict__ out,
                                        float scale)
{
    const float p2g = sums[0] * scale;
    const float g2p = sums[1] * scale;
    out[0] = p2g + g2p;
    out[1] = p2g;
    out[2] = g2p;
}

extern "C" void kernel_launch(void* const* d_in, const int* in_sizes, int n_in,
                              void* d_out, int out_size, void* d_ws, size_t ws_size,
                              hipStream_t stream) {
    const float* points = (const float*)d_in[0];   // [32][4096][3]
    const float* gts    = (const float*)d_in[1];   // [32][4096][3]
    float* out = (float*)d_out;
    float* ws  = (float*)d_ws;

    const int BS = 32;

    // ws layout: [0..1] sums, pad to 32B, then packed records (4 MB)
    float* sums   = ws;
    float* packed = ws + 8;   // 32B-aligned (SMEM x8/x16 merge friendly)

    hipMemsetAsync(sums, 0, 2 * sizeof(float), stream);

    pack_kernel<<<512, 256, 0, stream>>>(points, gts, packed);

    dim3 grid(NPTS / BLOCK, BS, 2);
    chamfer_main<<<grid, BLOCK, 0, stream>>>(points, gts, packed, sums);

    const float scale = 1.0f / (float)(BS * NPTS);
    chamfer_finalize_kernel<<<1, 1, 0, stream>>>(sums, out, scale);
}

// Round 5
// 109.822 us; speedup vs baseline: 1.0645x; 1.0645x over previous
//
#include <hip/hip_runtime.h>

typedef short short8 __attribute__((ext_vector_type(8)));
typedef float f32x16 __attribute__((ext_vector_type(16)));

#define NPTS 4096
#define NB   32
#define S    4        // pinned 32-point strips per wave

// ---- bf16 split helpers (round-to-nearest-even) ----
__device__ inline unsigned short bf16_rne(float v) {
    unsigned u = __float_as_uint(v);
    unsigned r = u + 0x7FFFu + ((u >> 16) & 1u);
    return (unsigned short)(r >> 16);
}
__device__ inline float bf16_to_f(unsigned short h) {
    return __uint_as_float(((unsigned)h) << 16);
}
__device__ inline void bf_split(float v, unsigned short& h, unsigned short& l) {
    h = bf16_rne(v);
    l = bf16_rne(v - bf16_to_f(h));
}

// ---- pre-pass: per point, 16-slot bf16 record (32B) for the streamed role ----
// b'' k-slots: [bh(x,y,z,1,hb), bl(x,y,z,0,hb), bh(x,y,z,1,hb), 0]
__global__ __launch_bounds__(256) void pack_kernel(
    const float* __restrict__ points, const float* __restrict__ gts,
    unsigned short* __restrict__ pk)
{
    const int tid = blockIdx.x * 256 + threadIdx.x;   // 0 .. 262143
    const int c   = tid >> 17;                        // cloud (131072 pts each)
    const int rem = tid & 131071;                     // b*4096 + j
    const float* src = (c ? gts : points) + (size_t)rem * 3;
    const float x = src[0], y = src[1], z = src[2];
    const float hb = x * x + y * y + z * z;
    unsigned short xh, xl, yh, yl, zh, zl, hh, hl;
    bf_split(x, xh, xl); bf_split(y, yh, yl);
    bf_split(z, zh, zl); bf_split(hb, hh, hl);
    const unsigned short ONE = 0x3F80;
    unsigned short r[16] = { xh, yh, zh, ONE, hh,
                             xl, yl, zl, 0,   hl,
                             xh, yh, zh, ONE, hh, 0 };
    int4* dst = (int4*)(pk + (size_t)tid * 16);
    int4 w0, w1;
    w0.x = r[0] | (r[1] << 16);  w0.y = r[2]  | (r[3]  << 16);
    w0.z = r[4] | (r[5] << 16);  w0.w = r[6]  | (r[7]  << 16);
    w1.x = r[8] | (r[9] << 16);  w1.y = r[10] | (r[11] << 16);
    w1.z = r[12]| (r[13]<< 16);  w1.w = r[14] | (r[15] << 16);
    dst[0] = w0; dst[1] = w1;
}

// ---- main: MFMA augmented-dot scan ----
__global__ __launch_bounds__(256) void chamfer_main(
    const float* __restrict__ points, const float* __restrict__ gts,
    const unsigned short* __restrict__ pk, float* __restrict__ sums)
{
    // XCD-swizzled 1-D grid: d = member*64 + group so one (dir,b)'s 8 blocks
    // share an XCD (L2-resident 128 KB stream).
    const int d      = blockIdx.x;        // 0..511
    const int group  = d & 63;            // (dir,b)
    const int member = d >> 6;            // A-chunk 0..7
    const int dir = group >> 5;
    const int b   = group & 31;

    const float* Ab = (dir ? gts : points) + (size_t)b * NPTS * 3;
    const int w = threadIdx.x >> 6, l = threadIdx.x & 63;
    const int half = l >> 5, c = l & 31;

    // pinned fragments (mfma B operand: col = lane&31, k = half*8 + e)
    // a'' k-slots: [ah(-2x,-2y,-2z,ha,1), ah(-2x,-2y,-2z), | ah(ha,1), al(-2x,-2y,-2z,ha), 0,0]
    short8 af[S];
    #pragma unroll
    for (int s = 0; s < S; ++s) {
        const int i = member * 512 + w * 128 + s * 32 + c;
        const float ax = Ab[i * 3 + 0], ay = Ab[i * 3 + 1], az = Ab[i * 3 + 2];
        const float ha = ax * ax + ay * ay + az * az;
        unsigned short xh, xl, yh, yl, zh, zl, hh, hl;
        bf_split(-2.f * ax, xh, xl);
        bf_split(-2.f * ay, yh, yl);
        bf_split(-2.f * az, zh, zl);
        bf_split(ha, hh, hl);
        const unsigned short ONE = 0x3F80;
        short8 f;
        if (half == 0) {
            f[0]=(short)xh; f[1]=(short)yh; f[2]=(short)zh; f[3]=(short)hh;
            f[4]=(short)ONE; f[5]=(short)xh; f[6]=(short)yh; f[7]=(short)zh;
        } else {
            f[0]=(short)hh; f[1]=(short)ONE; f[2]=(short)xl; f[3]=(short)yl;
            f[4]=(short)zl; f[5]=(short)hl; f[6]=0; f[7]=0;
        }
        af[s] = f;
    }

    // streamed cloud record pointer (mfma A operand: row = lane&31, k = half*8+e)
    const unsigned short* rec =
        pk + (((size_t)(dir ^ 1) * NB + b) * NPTS + (size_t)c) * 16 + half * 8;

    f32x16 zc;
    #pragma unroll
    for (int q = 0; q < 16; ++q) zc[q] = 0.f;

    float m[S] = {1e30f, 1e30f, 1e30f, 1e30f};

    short8 buf0 = *(const short8*)(rec);
    short8 buf1 = *(const short8*)(rec + 512);

    #pragma unroll 2
    for (int t = 0; t < NPTS / 32; ++t) {
        const short8 cur = buf0;
        buf0 = buf1;
        int tn = t + 2; if (tn > NPTS / 32 - 1) tn = NPTS / 32 - 1;
        buf1 = *(const short8*)(rec + (size_t)tn * 512);

        #pragma unroll
        for (int s = 0; s < S; ++s) {
            f32x16 acc = __builtin_amdgcn_mfma_f32_32x32x16_bf16(cur, af[s], zc, 0, 0, 0);
            #pragma unroll
            for (int q = 0; q < 8; ++q)
                asm("v_min3_f32 %0, %0, %1, %2"
                    : "+v"(m[s]) : "v"(acc[2 * q]), "v"(acc[2 * q + 1]));
        }
    }

    // epilogue: cross-half min, sqrt, sum
    float vsum = 0.f;
    #pragma unroll
    for (int s = 0; s < S; ++s) {
        const float other = __shfl_xor(m[s], 32);
        const float mm = fminf(m[s], other);
        vsum += sqrtf(fmaxf(mm, 0.f));
    }
    if (half) vsum = 0.f;                 // lanes 32-63 are duplicates
    for (int off = 32; off > 0; off >>= 1)
        vsum += __shfl_down(vsum, off);
    if (l == 0)
        atomicAdd(sums + dir, vsum);
}

__global__ void chamfer_finalize_kernel(const float* __restrict__ sums,
                                        float* __restrict__ out, float scale)
{
    const float p2g = sums[0] * scale;
    const float g2p = sums[1] * scale;
    out[0] = p2g + g2p;
    out[1] = p2g;
    out[2] = g2p;
}

extern "C" void kernel_launch(void* const* d_in, const int* in_sizes, int n_in,
                              void* d_out, int out_size, void* d_ws, size_t ws_size,
                              hipStream_t stream) {
    const float* points = (const float*)d_in[0];   // [32][4096][3]
    const float* gts    = (const float*)d_in[1];   // [32][4096][3]
    float* out = (float*)d_out;
    float* ws  = (float*)d_ws;

    float* sums = ws;                                  // [2]
    unsigned short* packed = (unsigned short*)(ws + 16);  // 64B-aligned, 8 MB

    hipMemsetAsync(sums, 0, 2 * sizeof(float), stream);

    pack_kernel<<<2 * NB * NPTS / 256, 256, 0, stream>>>(points, gts, packed);

    chamfer_main<<<512, 256, 0, stream>>>(points, gts, packed, sums);

    const float scale = 1.0f / (float)(NB * NPTS);
    chamfer_finalize_kernel<<<1, 1, 0, stream>>>(sums, out, scale);
}

// Round 6
// 76.782 us; speedup vs baseline: 1.5225x; 1.4303x over previous
//
#include <hip/hip_runtime.h>

typedef short short8 __attribute__((ext_vector_type(8)));
typedef float f32x16 __attribute__((ext_vector_type(16)));

#define NPTS 4096
#define NB   32
#define S    4        // pinned 32-point strips per wave
#define CHUNKS 4
#define BPTS (NPTS / CHUNKS)   // 1024 B-points per block
#define NT (BPTS / 32)         // 32 scan iterations

// ---- bf16 split helpers (round-to-nearest-even) ----
__device__ inline unsigned short bf16_rne(float v) {
    unsigned u = __float_as_uint(v);
    unsigned r = u + 0x7FFFu + ((u >> 16) & 1u);
    return (unsigned short)(r >> 16);
}
__device__ inline float bf16_to_f(unsigned short h) {
    return __uint_as_float(((unsigned)h) << 16);
}
__device__ inline void bf_split(float v, unsigned short& h, unsigned short& l) {
    h = bf16_rne(v);
    l = bf16_rne(v - bf16_to_f(h));
}

// ---- pre-pass: per point, 16-slot bf16 record (32B); also init mins to +big ----
__global__ __launch_bounds__(256) void pack_kernel(
    const float* __restrict__ points, const float* __restrict__ gts,
    unsigned short* __restrict__ pk, unsigned* __restrict__ minsInit)
{
    const int tid = blockIdx.x * 256 + threadIdx.x;   // 0 .. 262143
    const int c   = tid >> 17;                        // cloud
    const int rem = tid & 131071;                     // b*4096 + j
    const float* src = (c ? gts : points) + (size_t)rem * 3;
    const float x = src[0], y = src[1], z = src[2];
    const float hb = x * x + y * y + z * z;
    unsigned short xh, xl, yh, yl, zh, zl, hh, hl;
    bf_split(x, xh, xl); bf_split(y, yh, yl);
    bf_split(z, zh, zl); bf_split(hb, hh, hl);
    const unsigned short ONE = 0x3F80;
    unsigned short r[16] = { xh, yh, zh, ONE, hh,
                             xl, yl, zl, 0,   hl,
                             xh, yh, zh, ONE, hh, 0 };
    int4* dst = (int4*)(pk + (size_t)tid * 16);
    int4 w0, w1;
    w0.x = r[0] | (r[1] << 16);  w0.y = r[2]  | (r[3]  << 16);
    w0.z = r[4] | (r[5] << 16);  w0.w = r[6]  | (r[7]  << 16);
    w1.x = r[8] | (r[9] << 16);  w1.y = r[10] | (r[11] << 16);
    w1.z = r[12]| (r[13]<< 16);  w1.w = r[14] | (r[15] << 16);
    dst[0] = w0; dst[1] = w1;
    minsInit[tid] = 0x7F7FFFFFu;   // FLT_MAX
}

// ---- main: MFMA augmented-dot scan over one 1024-point B chunk ----
__global__ __launch_bounds__(256) void chamfer_main(
    const float* __restrict__ points, const float* __restrict__ gts,
    const unsigned short* __restrict__ pk, float* __restrict__ mins)
{
    const int d      = blockIdx.x;        // 0..2047
    const int group  = d & 63;            // (dir,b) — stride-64 blocks share XCD
    const int member = (d >> 6) & 7;      // A-chunk 0..7
    const int chunk  = d >> 9;            // B-chunk 0..3
    const int dir = group >> 5;
    const int b   = group & 31;

    const float* Ab = (dir ? gts : points) + (size_t)b * NPTS * 3;
    const int w = threadIdx.x >> 6, l = threadIdx.x & 63;
    const int half = l >> 5, c = l & 31;

    // pinned fragments (mfma B operand) — packing identical to verified R5
    short8 af[S];
    #pragma unroll
    for (int s = 0; s < S; ++s) {
        const int i = member * 512 + w * 128 + s * 32 + c;
        const float ax = Ab[i * 3 + 0], ay = Ab[i * 3 + 1], az = Ab[i * 3 + 2];
        const float ha = ax * ax + ay * ay + az * az;
        unsigned short xh, xl, yh, yl, zh, zl, hh, hl;
        bf_split(-2.f * ax, xh, xl);
        bf_split(-2.f * ay, yh, yl);
        bf_split(-2.f * az, zh, zl);
        bf_split(ha, hh, hl);
        const unsigned short ONE = 0x3F80;
        short8 f;
        if (half == 0) {
            f[0]=(short)xh; f[1]=(short)yh; f[2]=(short)zh; f[3]=(short)hh;
            f[4]=(short)ONE; f[5]=(short)xh; f[6]=(short)yh; f[7]=(short)zh;
        } else {
            f[0]=(short)hh; f[1]=(short)ONE; f[2]=(short)xl; f[3]=(short)yl;
            f[4]=(short)zl; f[5]=(short)hl; f[6]=0; f[7]=0;
        }
        af[s] = f;
    }

    // streamed records for this block's B chunk
    const unsigned short* rec =
        pk + (((size_t)(dir ^ 1) * NB + b) * NPTS + (size_t)chunk * BPTS + c) * 16
           + half * 8;

    f32x16 zc;
    #pragma unroll
    for (int q = 0; q < 16; ++q) zc[q] = 0.f;

    float mA[S] = {1e30f, 1e30f, 1e30f, 1e30f};
    float mB[S] = {1e30f, 1e30f, 1e30f, 1e30f};

    short8 buf0 = *(const short8*)(rec);
    short8 buf1 = *(const short8*)(rec + 512);

    #pragma unroll
    for (int t = 0; t < NT; ++t) {
        const int tn = (t + 2 < NT) ? (t + 2) : (NT - 1);   // constant-folded
        const short8 nb = *(const short8*)(rec + (size_t)tn * 512);
        const short8 cur = buf0;

        #pragma unroll
        for (int s = 0; s < S; ++s) {
            f32x16 acc = __builtin_amdgcn_mfma_f32_32x32x16_bf16(cur, af[s], zc, 0, 0, 0);
            #pragma unroll
            for (int q = 0; q < 4; ++q) {
                asm("v_min3_f32 %0, %0, %1, %2"
                    : "+v"(mA[s]) : "v"(acc[4 * q + 0]), "v"(acc[4 * q + 1]));
                asm("v_min3_f32 %0, %0, %1, %2"
                    : "+v"(mB[s]) : "v"(acc[4 * q + 2]), "v"(acc[4 * q + 3]));
            }
        }
        buf0 = buf1; buf1 = nb;   // SSA-renamed under full unroll
    }

    // combine chains + halves, clamp, publish partial min
    unsigned* minsU = (unsigned*)mins;
    #pragma unroll
    for (int s = 0; s < S; ++s) {
        float mm = fminf(mA[s], mB[s]);
        mm = fminf(mm, __shfl_xor(mm, 32));
        mm = fmaxf(mm, 0.f);                    // uint-order == float-order
        if (half == 0) {
            const int ap = member * 512 + w * 128 + s * 32 + c;
            atomicMin(&minsU[(size_t)group * NPTS + ap], __float_as_uint(mm));
        }
    }
}

// ---- pass 2: sqrt + sum per direction ----
__global__ __launch_bounds__(256) void reduce_kernel(
    const float* __restrict__ mins, float* __restrict__ sums)
{
    const int tid = blockIdx.x * 256 + threadIdx.x;   // 0..262143
    const int dir = tid >> 17;                        // uniform per block
    float v = sqrtf(mins[tid]);
    for (int off = 32; off > 0; off >>= 1)
        v += __shfl_down(v, off);
    __shared__ float wsum[4];
    const int w = threadIdx.x >> 6, l = threadIdx.x & 63;
    if (l == 0) wsum[w] = v;
    __syncthreads();
    if (threadIdx.x == 0)
        atomicAdd(sums + dir, wsum[0] + wsum[1] + wsum[2] + wsum[3]);
}

__global__ void chamfer_finalize_kernel(const float* __restrict__ sums,
                                        float* __restrict__ out, float scale)
{
    const float p2g = sums[0] * scale;
    const float g2p = sums[1] * scale;
    out[0] = p2g + g2p;
    out[1] = p2g;
    out[2] = g2p;
}

extern "C" void kernel_launch(void* const* d_in, const int* in_sizes, int n_in,
                              void* d_out, int out_size, void* d_ws, size_t ws_size,
                              hipStream_t stream) {
    const float* points = (const float*)d_in[0];   // [32][4096][3]
    const float* gts    = (const float*)d_in[1];   // [32][4096][3]
    float* out = (float*)d_out;
    float* ws  = (float*)d_ws;

    float* sums = ws;                                        // 8 B
    unsigned short* packed = (unsigned short*)(ws + 16);     // +64 B, 8 MB
    float* mins = (float*)((char*)d_ws + 64 + 8388608);      // 1 MB

    hipMemsetAsync(sums, 0, 2 * sizeof(float), stream);

    pack_kernel<<<1024, 256, 0, stream>>>(points, gts, packed, (unsigned*)mins);
    chamfer_main<<<2048, 256, 0, stream>>>(points, gts, packed, mins);
    reduce_kernel<<<1024, 256, 0, stream>>>(mins, sums);

    const float scale = 1.0f / (float)(NB * NPTS);
    chamfer_finalize_kernel<<<1, 1, 0, stream>>>(sums, out, scale);
}